// Round 1
// baseline (103.319 us; speedup 1.0000x reference)
//
#include <hip/hip_runtime.h>
#include <hip/hip_bf16.h>

#define IDIM 64
#define RDIM 36
#define DDIM 1024
#define CDIM 64
#define WDIM 32
#define SMOOTH 9.0f
#define EPSF 1e-8f

typedef __bf16 bf16_t;
typedef __bf16 bf16x8 __attribute__((ext_vector_type(8)));
typedef __bf16 bf16x4 __attribute__((ext_vector_type(4)));
typedef float f32x4 __attribute__((ext_vector_type(4)));

#define MFMA16(a, b, c) __builtin_amdgcn_mfma_f32_16x16x32_bf16((a), (b), (c), 0, 0, 0)

// ---------- workspace layout (bytes) ----------
// imgsB: frag-permuted imgs, rows padded to 48 with zeros.
//   elem off = ((((i*4+wvk)*8+kk)*3+nt)*64 + lane)*8 ; lane=(qd*16+l15)
// capsA: ((((c*4+wvk)*8+kk)*2+mt)*64 + lane)*8
// Gramf: f32 symmetric Gram per image, [i][48][48] row-major (atomic-accumulated)
// capn2: f32 sum-of-squares per caption word [c][32] (atomic-accumulated)
#define IMGSB_OFF 0
#define IMGSB_BYTES (IDIM * 4 * 12288 * 2)            // 6 MB
#define CAPSA_OFF (IMGSB_OFF + IMGSB_BYTES)
#define CAPSA_BYTES (CDIM * 4 * 8192 * 2)             // 4 MB
#define GRAM_OFF (CAPSA_OFF + CAPSA_BYTES)
#define GRAM_BYTES (IDIM * 48 * 48 * 4)               // 576 KB
#define CAPN2_OFF (GRAM_OFF + GRAM_BYTES)
#define CAPN2_BYTES (CDIM * WDIM * 4)                 // 8 KB

// =====================================================================
// Kernel 1: prep2 — 512 blocks, one (image|caption, K-slice) each.
// Blocks 0..255: (i = b>>2, wvk = b&3): fp32->bf16 transpose/convert of a
//   36x256 slice, frag-write to global + LDS copy; partial 48x48 Gram via
//   MFMA over this slice's 256 k's; f32 atomicAdd into Gramf[i].
// Blocks 256..511: (c, wvk): caps slice convert + partial row sumsq
//   atomicAdd into capn2.
// vs old prep_fused (128 blocks, 134 KB LDS -> 1 block/CU, half chip idle,
// 8 serialized barriers/img): full-chip, 2 blocks/CU, 3 barriers.
// =====================================================================
__global__ __launch_bounds__(256, 2) void prep2(
    const float* __restrict__ imgs, const float* __restrict__ caps,
    bf16_t* __restrict__ imgsB, bf16_t* __restrict__ capsA,
    float* __restrict__ Gramf, float* __restrict__ capn2) {
  __shared__ __align__(16) char smem0[4 * 48 * 49 * 4];   // ldsb | part overlay (37.6 KB)
  __shared__ __align__(16) bf16_t fragL[12288];           // 24 KB frag copy (one slice)
  bf16_t* ldsb = (bf16_t*)smem0;                          // [rows][264]
  float (*part)[48][49] = (float(*)[48][49])smem0;        // [4][48][49]

  int b = blockIdx.x, tid = threadIdx.x;
  int wv = tid >> 6, ln = tid & 63;
  int l15 = ln & 15, qd = ln >> 4;

  if (b < 256) {
    int i = b >> 2, wvk = b & 3;
    const float* src = imgs + (size_t)i * RDIM * DDIM + wvk * 256;
    // ---- phase 1: convert 36x256 slice into LDS ----
#pragma unroll
    for (int rep = 0; rep < 9; ++rep) {          // 36 rows x 64 float4
      int idx = rep * 256 + tid;
      int row = idx >> 6, q = idx & 63;
      float4 v = *(const float4*)(src + (size_t)row * DDIM + q * 4);
      bf16x4 p;
      p[0] = (bf16_t)v.x; p[1] = (bf16_t)v.y; p[2] = (bf16_t)v.z; p[3] = (bf16_t)v.w;
      *(bf16x4*)&ldsb[row * 264 + q * 4] = p;
    }
    __syncthreads();
    // ---- phase 2: frag permute -> global + LDS copy ----
    bf16_t* dst = imgsB + (size_t)(i * 4 + wvk) * 12288;
#pragma unroll
    for (int rep = 0; rep < 6; ++rep) {          // 1536 frag units of 8
      int u = rep * 256 + tid;
      int kk = u / 192, rem = u - kk * 192;
      int nt = rem >> 6, lane = rem & 63, qd2 = lane >> 4, l152 = lane & 15;
      int row = nt * 16 + l152;
      bf16x8 p;
      if (row < 36) {
        p = *(const bf16x8*)&ldsb[row * 264 + kk * 32 + qd2 * 8];
      } else {
#pragma unroll
        for (int j = 0; j < 8; ++j) p[j] = (bf16_t)0.0f;
      }
      *(bf16x8*)(dst + (size_t)u * 8) = p;       // global, coalesced
      *(bf16x8*)&fragL[u * 8] = p;               // LDS copy for gram
    }
    __syncthreads();
    // ---- phase 3: partial Gram; wave wv takes ksteps 2wv, 2wv+1 ----
    f32x4 acc[3][3];
#pragma unroll
    for (int mt = 0; mt < 3; ++mt)
#pragma unroll
      for (int nt = 0; nt < 3; ++nt) {
        f32x4 zf = {0.f, 0.f, 0.f, 0.f};
        acc[mt][nt] = zf;
      }
#pragma unroll
    for (int t = 0; t < 2; ++t) {
      int kk = wv * 2 + t;
      bf16x8 a[3];
#pragma unroll
      for (int nt = 0; nt < 3; ++nt)
        a[nt] = *(const bf16x8*)&fragL[((kk * 3 + nt) * 64 + ln) * 8];
#pragma unroll
      for (int mt = 0; mt < 3; ++mt)
#pragma unroll
        for (int nt = 0; nt < 3; ++nt)
          acc[mt][nt] = MFMA16(a[mt], a[nt], acc[mt][nt]);
    }
#pragma unroll
    for (int mt = 0; mt < 3; ++mt)
#pragma unroll
      for (int nt = 0; nt < 3; ++nt)
#pragma unroll
        for (int rg = 0; rg < 4; ++rg)
          part[wv][mt * 16 + qd * 4 + rg][nt * 16 + l15] = acc[mt][nt][rg];
    __syncthreads();
    // ---- phase 4: reduce 4 waves' partials, atomicAdd to Gramf[i] ----
    float* gp = Gramf + (size_t)i * 2304;
#pragma unroll
    for (int it = 0; it < 9; ++it) {             // 2304 = 9 * 256
      int u = it * 256 + tid;
      int r = u / 48, cc = u - r * 48;
      float v = part[0][r][cc] + part[1][r][cc] + part[2][r][cc] + part[3][r][cc];
      atomicAdd(gp + u, v);
    }
  } else {
    // ---- caps slice: convert + partial fp32 row sumsq ----
    int bb = b - 256;
    int c = bb >> 2, wvk = bb & 3;
    const float* src = caps + (size_t)c * WDIM * DDIM + wvk * 256;
    float ss[8];
#pragma unroll
    for (int rep = 0; rep < 8; ++rep) ss[rep] = 0.f;
#pragma unroll
    for (int rep = 0; rep < 8; ++rep) {          // 32 rows x 64 float4
      int idx = rep * 256 + tid;
      int row = idx >> 6, q = idx & 63;
      float4 v = *(const float4*)(src + (size_t)row * DDIM + q * 4);
      ss[rep] += v.x * v.x + v.y * v.y + v.z * v.z + v.w * v.w;
      bf16x4 p;
      p[0] = (bf16_t)v.x; p[1] = (bf16_t)v.y; p[2] = (bf16_t)v.z; p[3] = (bf16_t)v.w;
      *(bf16x4*)&ldsb[row * 264 + q * 4] = p;
    }
    __syncthreads();
    bf16_t* dst = capsA + (size_t)(c * 4 + wvk) * 8192;
#pragma unroll
    for (int rep = 0; rep < 4; ++rep) {          // 1024 frag units
      int u = rep * 256 + tid;
      int kk = u >> 7, rem = u & 127;
      int mt = rem >> 6, lane = rem & 63, qd2 = lane >> 4, l152 = lane & 15;
      int row = mt * 16 + l152;
      bf16x8 p = *(const bf16x8*)&ldsb[row * 264 + kk * 32 + qd2 * 8];
      *(bf16x8*)(dst + (size_t)u * 8) = p;
    }
#pragma unroll
    for (int rep = 0; rep < 8; ++rep) {          // row = rep*4 + wv
      float s = ss[rep];
#pragma unroll
      for (int off = 32; off >= 1; off >>= 1) s += __shfl_xor(s, off, 64);
      if (ln == 0) atomicAdd(&capn2[c * 32 + rep * 4 + wv], s);
    }
  }
}

// =====================================================================
// Kernel 2: main (R10 structure, verbatim except: G frags now built from
// f32 symmetric Gramf (G[k][n] = G[n][k], row-major reads), and capnorm
// is sqrtf(capn2)) — block = 4 waves = 4 c's x ONE i; B staged once into
// LDS via register double-buffer.
// =====================================================================
__global__ __launch_bounds__(256, 4) void main_kernel(
    const bf16_t* __restrict__ capsA, const bf16_t* __restrict__ imgsB,
    const float* __restrict__ Gramf, const float* __restrict__ capn2,
    const int* __restrict__ cap_lens, float* __restrict__ out) {
  __shared__ __align__(16) bf16_t ldsB[2][6144];   // 24.6 KB B chunks / attn scratch

  int bx = blockIdx.x;
  int wv = threadIdx.x >> 6, ln = threadIdx.x & 63;
  int l15 = ln & 15, qd = ln >> 4;
  int xcd = bx & 7, rest = bx >> 3;
  int ih = rest & 7, cq = rest >> 3;
  int i = xcd * 8 + ih;                 // XCD keeps an 8-image octet L2-resident
  int c = cq * 4 + wv;
  int clen = cap_lens[c];

  const bf16_t* Ab = capsA + (size_t)c * 32768;
  const bf16_t* Bb = imgsB + (size_t)i * 49152;

  // stage chunk 0 (each wave copies its 1536-elem quarter)
  bf16x8 t0, t1, t2;
  {
    const bf16_t* gp = Bb + wv * 1536 + ln * 8;
    t0 = *(const bf16x8*)(gp);
    t1 = *(const bf16x8*)(gp + 512);
    t2 = *(const bf16x8*)(gp + 1024);
    bf16_t* lp = &ldsB[0][wv * 1536 + ln * 8];
    *(bf16x8*)(lp) = t0;
    *(bf16x8*)(lp + 512) = t1;
    *(bf16x8*)(lp + 1024) = t2;
  }
  __syncthreads();

  f32x4 acc[2][3];
#pragma unroll
  for (int mt = 0; mt < 2; ++mt)
#pragma unroll
    for (int nt = 0; nt < 3; ++nt) {
      f32x4 zf = {0.f, 0.f, 0.f, 0.f};
      acc[mt][nt] = zf;
    }

  for (int ch = 0; ch < 8; ++ch) {
    int p = ch & 1;
    if (ch < 7) {  // prefetch next chunk quarter into regs
      const bf16_t* gp = Bb + (ch + 1) * 6144 + wv * 1536 + ln * 8;
      t0 = *(const bf16x8*)(gp);
      t1 = *(const bf16x8*)(gp + 512);
      t2 = *(const bf16x8*)(gp + 1024);
    }
#pragma unroll
    for (int j = 0; j < 4; ++j) {
      int s = ch * 4 + j;
      const bf16_t* ap = Ab + (size_t)s * 1024 + ln * 8;
      bf16x8 a0 = *(const bf16x8*)(ap);
      bf16x8 a1 = *(const bf16x8*)(ap + 512);
      const bf16_t* lp = &ldsB[p][j * 1536 + ln * 8];
      bf16x8 b0 = *(const bf16x8*)(lp);
      bf16x8 b1 = *(const bf16x8*)(lp + 512);
      bf16x8 b2 = *(const bf16x8*)(lp + 1024);
      acc[0][0] = MFMA16(a0, b0, acc[0][0]);
      acc[0][1] = MFMA16(a0, b1, acc[0][1]);
      acc[0][2] = MFMA16(a0, b2, acc[0][2]);
      acc[1][0] = MFMA16(a1, b0, acc[1][0]);
      acc[1][1] = MFMA16(a1, b1, acc[1][1]);
      acc[1][2] = MFMA16(a1, b2, acc[1][2]);
    }
    if (ch < 7) {
      bf16_t* lp = &ldsB[1 - p][wv * 1536 + ln * 8];
      *(bf16x8*)(lp) = t0;
      *(bf16x8*)(lp + 512) = t1;
      *(bf16x8*)(lp + 1024) = t2;
    }
    __syncthreads();
  }

  // ---- G frags from f32 symmetric Gram (latency hides behind w-norm) ----
  // need B-frag ga[kk][nt][j] = G[k][n], k = kk*32+qd*8+j, n = nt*16+l15;
  // k in [48,64) is zero pad; else G[k][n] = G[n][k] (symmetric) = row-major
  // contiguous 8 floats at Gb[n*48 + kk*32 + qd*8].
  const float* Gb = Gramf + (size_t)i * 2304;
  bf16x8 ga[2][3];
#pragma unroll
  for (int kk = 0; kk < 2; ++kk)
#pragma unroll
    for (int nt = 0; nt < 3; ++nt) {
      bf16x8 g;
      if (kk == 1 && qd >= 2) {                  // k >= 48: zero pad
#pragma unroll
        for (int j = 0; j < 8; ++j) g[j] = (bf16_t)0.0f;
      } else {
        const float* gp = Gb + (nt * 16 + l15) * 48 + kk * 32 + qd * 8;
        f32x4 u0 = *(const f32x4*)(gp);
        f32x4 u1 = *(const f32x4*)(gp + 4);
        g[0] = (bf16_t)u0[0]; g[1] = (bf16_t)u0[1];
        g[2] = (bf16_t)u0[2]; g[3] = (bf16_t)u0[3];
        g[4] = (bf16_t)u1[0]; g[5] = (bf16_t)u1[1];
        g[6] = (bf16_t)u1[2]; g[7] = (bf16_t)u1[3];
      }
      ga[kk][nt] = g;
    }

  // ---- w-norm: sum_m leaky(raw)^2 per column ----
  float sinv[3];
#pragma unroll
  for (int nt = 0; nt < 3; ++nt) {
    bool padn = (nt == 2) && (l15 >= 4);
    float ns = 0.f;
#pragma unroll
    for (int mt = 0; mt < 2; ++mt)
#pragma unroll
      for (int rg = 0; rg < 4; ++rg) {
        float v = acc[mt][nt][rg];
        float l = (v > 0.f) ? v : 0.1f * v;
        int m = mt * 16 + qd * 4 + rg;
        if (m >= clen || padn) l = 0.f;
        ns += l * l;
      }
    ns += __shfl_xor(ns, 16, 64);
    ns += __shfl_xor(ns, 32, 64);
    sinv[nt] = SMOOTH / (sqrtf(ns) + EPSF);
  }

  // ---- softmax over r per row + S = sum attn*raw; acc := softmax wts ----
  float Srow[2][4];
#pragma unroll
  for (int mt = 0; mt < 2; ++mt)
#pragma unroll
    for (int rg = 0; rg < 4; ++rg) {
      int m = mt * 16 + qd * 4 + rg;
      bool mrow = (m >= clen);
      float z[3];
#pragma unroll
      for (int nt = 0; nt < 3; ++nt) {
        float v = acc[mt][nt][rg];
        float l = (v > 0.f) ? v : 0.1f * v;
        if (mrow) l = 0.f;
        float zz = l * sinv[nt];
        if (nt == 2 && l15 >= 4) zz = -1e30f;
        z[nt] = zz;
      }
      float mx = fmaxf(fmaxf(z[0], z[1]), z[2]);
#pragma unroll
      for (int off = 1; off < 16; off <<= 1) mx = fmaxf(mx, __shfl_xor(mx, off, 64));
      float e[3], es = 0.f;
#pragma unroll
      for (int nt = 0; nt < 3; ++nt) {
        e[nt] = __expf(z[nt] - mx);
        es += e[nt];
      }
#pragma unroll
      for (int off = 1; off < 16; off <<= 1) es += __shfl_xor(es, off, 64);
      float inv = 1.0f / es;
      float sac = 0.f;
#pragma unroll
      for (int nt = 0; nt < 3; ++nt) {
        float a = e[nt] * inv;
        sac += a * acc[mt][nt][rg];   // raw before overwrite
        acc[mt][nt][rg] = a;          // softmax weight
      }
#pragma unroll
      for (int off = 1; off < 16; off <<= 1) sac += __shfl_xor(sac, off, 64);
      Srow[mt][rg] = sac;
    }

  // ---- stage attn to scratch (A-frag order), within-wave only ----
  bf16_t* as = &ldsB[0][0] + wv * 2304;   // 32 rows x 72, per-wave region
#pragma unroll
  for (int mt = 0; mt < 2; ++mt)
#pragma unroll
    for (int nt = 0; nt < 3; ++nt)
#pragma unroll
      for (int rg = 0; rg < 4; ++rg)
        as[(mt * 16 + qd * 4 + rg) * 72 + nt * 16 + l15] = (bf16_t)acc[mt][nt][rg];
  {  // zero k in [48,64)
    bf16x8 z8;
#pragma unroll
    for (int q = 0; q < 8; ++q) z8[q] = (bf16_t)0.0f;
    *(bf16x8*)(as + (ln >> 1) * 72 + 48 + (ln & 1) * 8) = z8;
  }
  bf16x8 fa[2][2];
#pragma unroll
  for (int mt = 0; mt < 2; ++mt)
#pragma unroll
    for (int kk = 0; kk < 2; ++kk)
      fa[mt][kk] = *(const bf16x8*)(as + (mt * 16 + l15) * 72 + kk * 32 + qd * 8);

  // ---- Y = attn * G via MFMA; n2[m] = sum Y .* attn ----
  f32x4 y[2][3];
#pragma unroll
  for (int mt = 0; mt < 2; ++mt)
#pragma unroll
    for (int nt = 0; nt < 3; ++nt) {
      f32x4 zf = {0.f, 0.f, 0.f, 0.f};
      y[mt][nt] = zf;
    }
#pragma unroll
  for (int kk = 0; kk < 2; ++kk)
#pragma unroll
    for (int mt = 0; mt < 2; ++mt)
#pragma unroll
      for (int nt = 0; nt < 3; ++nt)
        y[mt][nt] = MFMA16(fa[mt][kk], ga[kk][nt], y[mt][nt]);

  float n2row[2][4];
#pragma unroll
  for (int mt = 0; mt < 2; ++mt)
#pragma unroll
    for (int rg = 0; rg < 4; ++rg) {
      float nn = 0.f;
#pragma unroll
      for (int nt = 0; nt < 3; ++nt) nn += y[mt][nt][rg] * acc[mt][nt][rg];
#pragma unroll
      for (int off = 1; off < 16; off <<= 1) nn += __shfl_xor(nn, off, 64);
      n2row[mt][rg] = nn;
    }

  // ---- final sim + store: lanes l15<2 write float4 each ----
  if (l15 < 2) {
    int mt = l15;
    f32x4 cn2 = *(const f32x4*)(capn2 + c * 32 + mt * 16 + qd * 4);
    f32x4 o;
#pragma unroll
    for (int rg = 0; rg < 4; ++rg) {
      float cnv = sqrtf(cn2[rg]);
      float n2v = fmaxf(n2row[mt][rg], 0.f);
      float nrm = sqrtf(n2v);
      float den = nrm + EPSF;
      float w12 = Srow[mt][rg] / den;
      float w2 = nrm / den;
      float sim = w12 / fmaxf(cnv * w2, EPSF);
      int m = mt * 16 + qd * 4 + rg;
      if (m >= clen) sim = -1.0f;
      o[rg] = sim;
    }
    *(f32x4*)(out + ((size_t)i * CDIM + c) * WDIM + mt * 16 + qd * 4) = o;
  }
}

// =====================================================================
extern "C" void kernel_launch(void* const* d_in, const int* in_sizes, int n_in,
                              void* d_out, int out_size, void* d_ws, size_t ws_size,
                              hipStream_t stream) {
  const float* imgs = (const float*)d_in[0];
  const float* caps = (const float*)d_in[1];
  const int* cap_lens = (const int*)d_in[3];
  float* out = (float*)d_out;

  char* ws = (char*)d_ws;
  bf16_t* imgsB = (bf16_t*)(ws + IMGSB_OFF);
  bf16_t* capsA = (bf16_t*)(ws + CAPSA_OFF);
  float* Gramf = (float*)(ws + GRAM_OFF);
  float* capn2 = (float*)(ws + CAPN2_OFF);

  // zero the atomic accumulators (Gramf + capn2 are contiguous)
  hipMemsetAsync(ws + GRAM_OFF, 0, GRAM_BYTES + CAPN2_BYTES, stream);
  prep2<<<512, 256, 0, stream>>>(imgs, caps, imgsB, capsA, Gramf, capn2);
  main_kernel<<<1024, 256, 0, stream>>>(capsA, imgsB, Gramf, capn2, cap_lens, out);
}